// Round 1
// baseline (218.296 us; speedup 1.0000x reference)
//
#include <hip/hip_runtime.h>
#include <math.h>

#define TPB 256

// Packed complex: clang ext_vector_type(2) float -> VOP3P v_pk_{add,mul,fma}_f32
typedef float cplx __attribute__((ext_vector_type(2)));

__device__ __forceinline__ cplx cmul(cplx a, cplx b) {
    // (a.x*b.x - a.y*b.y, a.x*b.y + a.y*b.x)
    return a.xx * b + cplx{-a.y, a.y} * b.yx;
}

// XOR swizzle on the complex (float2) index: wave64 b64 accesses hit each
// bank-pair exactly the 4-round minimum for 512 B. Works on any 16-aligned
// sub-block, so it is valid for the 2048-entry half buffer too.
__device__ __forceinline__ int sw2(int i) { return i ^ ((i >> 4) & 15); }

__device__ __forceinline__ void dft4(cplx& a, cplx& b, cplx& c, cplx& d) {
    cplx t0 = a + c, t1 = a - c, t2 = b + d, t3 = b - d;
    a = t0 + t2;
    c = t0 - t2;
    cplx jt3 = cplx{t3.y, -t3.x};   // -i * t3
    b = t1 + jt3;
    d = t1 - jt3;
}

// In-register 16-point DFT. Input v[l]; output y[m] lands at v[T16(m)].
// T16 is an involution (4x4 transpose), which lets us twiddle in place.
#define T16(j) (4 * ((j) & 3) + ((j) >> 2))

__device__ __forceinline__ void dft16(cplx v[16]) {
#pragma unroll
    for (int j = 0; j < 4; ++j) dft4(v[j], v[4 + j], v[8 + j], v[12 + j]);
    const float C1 = 0.9238795325112867f, S1 = 0.3826834323650898f;
    const float R2 = 0.7071067811865476f;
    v[5]  = cmul(v[5],  cplx{ C1, -S1});   // w16^1
    v[9]  = cmul(v[9],  cplx{ R2, -R2});   // w16^2
    v[13] = cmul(v[13], cplx{ S1, -C1});   // w16^3
    v[6]  = cmul(v[6],  cplx{ R2, -R2});   // w16^2
    v[10] = cplx{v[10].y, -v[10].x};       // * w16^4 = -i
    v[14] = cmul(v[14], cplx{-R2, -R2});   // w16^6
    v[7]  = cmul(v[7],  cplx{ S1, -C1});   // w16^3
    v[11] = cmul(v[11], cplx{-R2, -R2});   // w16^6
    v[15] = cmul(v[15], cplx{-C1,  S1});   // w16^9
#pragma unroll
    for (int b = 0; b < 4; ++b) dft4(v[4 * b], v[4 * b + 1], v[4 * b + 2], v[4 * b + 3]);
}

// LDS halved to 16 KiB (2048 cplx): 8 blocks/CU (wave-capped, 128 KiB LDS/CU)
// vs 5 before — the kernel is latency-bound (VALUBusy 42%, Occupancy 27%), so
// residency is the lever. Every transpose has g<2048 <=> t<128 (write side)
// and <=> l<8 (read side), so each exchange runs as two half-passes.
// min_waves stays 4: declaring higher drove the backend to spill in a past
// session; HW still co-schedules 8 blocks when VGPR<=64.
__global__ __launch_bounds__(TPB, 4) void snr_kernel(const float* __restrict__ x,
                                                     const float* __restrict__ targets,
                                                     float* __restrict__ out) {
    __shared__ __align__(16) cplx Z[2048];   // exactly 16384 B
    float* zf = (float*)Z;                   // overlay: Z[0..5] never touched by
                                             // the split exchange (all b >= 16)

    const int t = threadIdx.x;
    const int blk = blockIdx.x;
    const int u7 = t & 127;
    const bool lo = (t < 128);

    // ---- every thread computes r (uniform; no LDS broadcast needed) ----
    int r;
    {
        float tg = targets[blk];
        const float df = 0.00244140625f;  // 10/4096 exact; f[i] = i*df exact in fp32
        int c0 = (int)(tg * 409.6f) - 2;
        if (c0 < 0) c0 = 0;
        r = c0;
        float best = fabsf(df * (float)c0 - tg);
        for (int i = c0 + 1; i <= c0 + 4 && i <= 4096; ++i) {
            float dd = fabsf(df * (float)i - tg);
            if (dd < best) { best = dd; r = i; }  // strict <: first-min wins == argmin
        }
    }

    // ---- Load: thread t owns c[t + 256*l] (8B/lane, contiguous per wave) ----
    cplx a[16], b[16];
    const cplx* row = (const cplx*)(x + (size_t)blk * 8192);
#pragma unroll
    for (int l = 0; l < 16; ++l) a[l] = row[t + 256 * l];

    // ======== stage 0: s=1, n=4096; global dest g = 16t + m ========
    dft16(a);
    {
        float ang = -1.5339807878856412e-3f * (float)t;  // -2pi/4096 * t
        float sn, cs; __sincosf(ang, &sn, &cs);
        cplx w1 = cplx{cs, sn};
        cplx w2 = cmul(w1, w1), w3 = cmul(w2, w1);
        cplx w4 = cmul(w2, w2), w8 = cmul(w4, w4), w12 = cmul(w8, w4);
        cplx wa[4] = {cplx{1.f, 0.f}, w1, w2, w3};
        cplx wb[4] = {cplx{1.f, 0.f}, w4, w8, w12};
        // twiddle in place: register a[j] holds y[m], m = T16(j) (involution)
#pragma unroll
        for (int m = 1; m < 16; ++m) {
            int j = T16(m);
            a[j] = cmul(a[j], cmul(wb[m >> 2], wa[m & 3]));
        }
    }
    // exchange A (two half-passes through the 2048-cplx buffer)
    if (lo) {
#pragma unroll
        for (int j = 0; j < 16; ++j) Z[sw2(16 * u7 + T16(j))] = a[j];
    }
    __syncthreads();
#pragma unroll
    for (int l = 0; l < 8; ++l) b[l] = Z[sw2(t + 256 * l)];
    __syncthreads();
    if (!lo) {
#pragma unroll
        for (int j = 0; j < 16; ++j) Z[sw2(16 * u7 + T16(j))] = a[j];
    }
    __syncthreads();
#pragma unroll
    for (int l = 8; l < 16; ++l) b[l] = Z[sw2(t + 256 * (l - 8))];
    __syncthreads();

    // ======== stage 1: s=16, n=256; g = q + 256p + 16m ========
    dft16(b);
    {
        const int p = t >> 4;
        float ang = -0.02454369260617026f * (float)p;  // -2pi/256 * p
        float sn, cs; __sincosf(ang, &sn, &cs);
        cplx w1 = cplx{cs, sn};
        cplx w2 = cmul(w1, w1), w3 = cmul(w2, w1);
        cplx w4 = cmul(w2, w2), w8 = cmul(w4, w4), w12 = cmul(w8, w4);
        cplx wa[4] = {cplx{1.f, 0.f}, w1, w2, w3};
        cplx wb[4] = {cplx{1.f, 0.f}, w4, w8, w12};
#pragma unroll
        for (int m = 1; m < 16; ++m) {
            int j = T16(m);
            b[j] = cmul(b[j], cmul(wb[m >> 2], wa[m & 3]));
        }
    }
    {
        const int ebase = (t & 15) + ((t & 0x70) << 4);  // q + 256*(p&7)
        if (lo) {
#pragma unroll
            for (int j = 0; j < 16; ++j) Z[sw2(ebase + 16 * T16(j))] = b[j];
        }
        __syncthreads();
#pragma unroll
        for (int l = 0; l < 8; ++l) a[l] = Z[sw2(t + 256 * l)];
        __syncthreads();
        if (!lo) {
#pragma unroll
            for (int j = 0; j < 16; ++j) Z[sw2(ebase + 16 * T16(j))] = b[j];
        }
        __syncthreads();
#pragma unroll
        for (int l = 8; l < 16; ++l) a[l] = Z[sw2(t + 256 * (l - 8))];
        __syncthreads();
    }

    // ======== stage 2: s=256, p=0 (no twiddle); a[T16(m)] = Z[t+256m] ========
    dft16(a);

    // ======== rfft split, conjugate-pair fused ========
    // X[k] = 0.5(s - i*tt), X[4096-k] = conj(0.5(s + i*tt)) from the SAME
    // (s,tt). Only threads t>128 export their Z (2032 slots, ONE pass); threads
    // t<=128 compute BOTH bins of each pair. t=0 and t=128 self-pair in regs.
    if (t > 128) {
#pragma unroll
        for (int j = 0; j < 16; ++j) Z[sw2(16 * u7 + T16(j))] = a[j];
    }
    __syncthreads();

    const int r2 = 2 * r;
    float band = 0.f;
    float p1c = 0.f, p2c = 0.f, p1cn = 0.f, p2cn = 0.f;
    int d1c = -1, d2c = -1, d1cn = -1, d2cn = -1;
    if (t <= 128) {
        // t=0: pairs (m,16-m) -> only m<=8 (m=8 self-pairs at bin 2048, and a
        // duplicate 2r-cap write of the same value is benign; 2048 not in band).
        // t=128: pairs (m,15-m) -> only m<=7.
        const int mEnd = (t == 0) ? 9 : ((t == 128) ? 8 : 16);
        const int pb = 16 * ((128 - t) & 127);   // partner base (masked: in-bounds for t=0/128)
        float ang = -7.669903939428206e-4f * (float)t;  // -pi/4096 * t
        float sn, cs; __sincosf(ang, &sn, &cs);
        cplx wk = cplx{cs, sn};
        const cplx wstep = cplx{0.9807852804032304f, -0.19509032201612825f};  // e^{-i pi/16}
#pragma unroll
        for (int m = 0; m < 16; ++m) {
            if (m < mEnd) {
                const int k = t + 256 * m;
                const int nk = 4096 - k;
                cplx Zk = a[T16(m)];
                cplx Zn;
                if (t == 0)        Zn = a[T16((16 - m) & 15)];
                else if (t == 128) Zn = a[T16(15 - m)];
                else               Zn = Z[sw2(pb + (15 - m))];
                cplx Znc = cplx{Zn.x, -Zn.y};
                cplx s  = Zk + Znc;
                cplx dd = Zk - Znc;
                cplx tt = cmul(wk, dd);
                cplx Xk = s + cplx{ tt.y, -tt.x};   // 2*X[k]
                cplx Xn = s + cplx{-tt.y,  tt.x};   // 2*conj(X[4096-k])
                float Pk = (Xk.x * Xk.x + Xk.y * Xk.y) * (1.0f / 32768.0f);
                float Pn = (Xn.x * Xn.x + Xn.y * Xn.y) * (1.0f / 32768.0f);
                if ((unsigned)(k  - 273) <= 1433u) band += Pk;   // band [273,1706]
                if ((unsigned)(nk - 273) <= 1433u) band += Pn;
                int d1 = k  - (r - 1);  if ((unsigned)d1 < 3u) { d1c  = d1; p1c  = Pk; }
                int d2 = k  - (r2 - 1); if ((unsigned)d2 < 3u) { d2c  = d2; p2c  = Pk; }
                int e1 = nk - (r - 1);  if ((unsigned)e1 < 3u) { d1cn = e1; p1cn = Pn; }
                int e2 = nk - (r2 - 1); if ((unsigned)e2 < 3u) { d2cn = e2; p2cn = Pn; }
            }
            wk = cmul(wk, wstep);
        }
    }

    // zf overlay (Z[0..5]) is disjoint from all split-exchange addresses
    // (b >= 16), so no extra barrier is needed before these writes.
    if (d1c  >= 0) zf[d1c]      = p1c;
    if (d2c  >= 0) zf[3 + d2c]  = p2c;
    if (d1cn >= 0) zf[d1cn]     = p1cn;
    if (d2cn >= 0) zf[3 + d2cn] = p2cn;

    // ---- block reduce band ----
#pragma unroll
    for (int off = 32; off > 0; off >>= 1) band += __shfl_down(band, off);
    if ((t & 63) == 0) zf[8 + (t >> 6)] = band;
    __syncthreads();

    if (t == 0) {
        float bb = zf[8] + zf[9] + zf[10] + zf[11];
        float S = zf[1] + zf[4] + 0.5f * (zf[0] + zf[2]);
        float noise = bb;
        if (r <= 1706)      noise -= zf[1];
        if (r - 1 >= 273)   noise -= 0.5f * zf[0];
        if (r + 1 <= 1706)  noise -= 0.5f * zf[2];
        if (r2 - 1 <= 1706) noise -= zf[3];
        if (r2 <= 1706)     noise -= zf[4];
        if (r2 + 1 <= 1706) noise -= zf[5];
        float loss = -10.0f * log10f(S / (noise + 1.0f));
        atomicAdd(out, loss * (1.0f / 4096.0f));
    }
}

extern "C" void kernel_launch(void* const* d_in, const int* in_sizes, int n_in,
                              void* d_out, int out_size, void* d_ws, size_t ws_size,
                              hipStream_t stream) {
    const float* x = (const float*)d_in[0];    // outputs: (4096, 8192) fp32
    const float* tg = (const float*)d_in[1];   // targets: (4096, 1) fp32
    float* out = (float*)d_out;                // scalar fp32
    hipMemsetAsync(out, 0, sizeof(float), stream);
    snr_kernel<<<4096, TPB, 0, stream>>>(x, tg, out);
}

// Round 2
// 209.220 us; speedup vs baseline: 1.0434x; 1.0434x over previous
//
#include <hip/hip_runtime.h>
#include <math.h>

#define TPB 256

// Packed complex: clang ext_vector_type(2) float -> VOP3P v_pk_{add,mul,fma}_f32
typedef float cplx __attribute__((ext_vector_type(2)));

__device__ __forceinline__ cplx cmul(cplx a, cplx b) {
    // (a.x*b.x - a.y*b.y, a.x*b.y + a.y*b.x)
    return a.xx * b + cplx{-a.y, a.y} * b.yx;
}

__device__ __forceinline__ void dft4(cplx& a, cplx& b, cplx& c, cplx& d) {
    cplx t0 = a + c, t1 = a - c, t2 = b + d, t3 = b - d;
    a = t0 + t2;
    c = t0 - t2;
    cplx jt3 = cplx{t3.y, -t3.x};   // -i * t3
    b = t1 + jt3;
    d = t1 - jt3;
}

// In-register 16-point DFT. Input v[l]; output y[m] lands at v[T16(m)].
// T16 is an involution (4x4 transpose) -> twiddle in place, write from a[j].
#define T16(j) (4 * ((j) & 3) + ((j) >> 2))

__device__ __forceinline__ void dft16(cplx v[16]) {
#pragma unroll
    for (int j = 0; j < 4; ++j) dft4(v[j], v[4 + j], v[8 + j], v[12 + j]);
    const float C1 = 0.9238795325112867f, S1 = 0.3826834323650898f;
    const float R2 = 0.7071067811865476f;
    v[5]  = cmul(v[5],  cplx{ C1, -S1});   // w16^1
    v[9]  = cmul(v[9],  cplx{ R2, -R2});   // w16^2
    v[13] = cmul(v[13], cplx{ S1, -C1});   // w16^3
    v[6]  = cmul(v[6],  cplx{ R2, -R2});   // w16^2
    v[10] = cplx{v[10].y, -v[10].x};       // * w16^4 = -i
    v[14] = cmul(v[14], cplx{-R2, -R2});   // w16^6
    v[7]  = cmul(v[7],  cplx{ S1, -C1});   // w16^3
    v[11] = cmul(v[11], cplx{-R2, -R2});   // w16^6
    v[15] = cmul(v[15], cplx{-C1,  S1});   // w16^9
#pragma unroll
    for (int b = 0; b < 4; ++b) dft4(v[4 * b], v[4 * b + 1], v[4 * b + 2], v[4 * b + 3]);
}

// Swizzle closed forms (sw2(i) = i ^ ((i>>4)&15)):
//   read  slots t+256l      : phys = (t ^ ((t>>4)&15)) + 256l      (XOR l-invariant)
//   stage0/export 16t+m     : phys = 16t + (m ^ (t&15))
//   stage1 write q+16m+256p : phys = 256p + 16m + (q^m)
//   bin b lives at logical 16(b&255)+(b>>8) -> phys 16(b&255) + ((b>>8)^(b&15))
//
// Occupancy theory DISPROVEN in R1 (16KB/8-blk: occ 27->47%, dur 79->85us,
// VALUBusy down). Kernel is issue/critical-path bound -> back to 32KB one-pass
// exchanges; this round cuts VALU work (balanced 6-iter split, post-hoc caps).
__global__ __launch_bounds__(TPB, 4) void snr_kernel(const float* __restrict__ x,
                                                     const float* __restrict__ targets,
                                                     float* __restrict__ out) {
    __shared__ __align__(16) cplx Z[4096];   // 32768 B
    float* zf = (float*)Z;                   // overlay AFTER final sync: caps [0..5], red [8..11]

    const int t = threadIdx.x;
    const int blk = blockIdx.x;
    const int tl = t & 15;

    // ---- every thread computes r (uniform; no LDS broadcast needed) ----
    int r;
    {
        float tg = targets[blk];
        const float df = 0.00244140625f;  // 10/4096 exact; f[i] = i*df exact in fp32
        int c0 = (int)(tg * 409.6f) - 2;
        if (c0 < 0) c0 = 0;
        r = c0;
        float best = fabsf(df * (float)c0 - tg);
        for (int i = c0 + 1; i <= c0 + 4 && i <= 4096; ++i) {
            float dd = fabsf(df * (float)i - tg);
            if (dd < best) { best = dd; r = i; }  // strict <: first-min wins == argmin
        }
    }

    // ---- Load: thread t owns c[t + 256*l] (8B/lane, contiguous per wave) ----
    cplx a[16];
    const cplx* row = (const cplx*)(x + (size_t)blk * 8192);
#pragma unroll
    for (int l = 0; l < 16; ++l) a[l] = row[t + 256 * l];

    // ======== stage 0: s=1, n=4096; logical dest g = 16t + m ========
    dft16(a);
    {
        float ang = -1.5339807878856412e-3f * (float)t;  // -2pi/4096 * t
        float sn, cs; __sincosf(ang, &sn, &cs);
        cplx w1 = cplx{cs, sn};
        cplx w2 = cmul(w1, w1), w3 = cmul(w2, w1);
        cplx w4 = cmul(w2, w2), w8 = cmul(w4, w4), w12 = cmul(w8, w4);
        cplx wa[4] = {cplx{1.f, 0.f}, w1, w2, w3};
        cplx wb[4] = {cplx{1.f, 0.f}, w4, w8, w12};
#pragma unroll
        for (int m = 1; m < 16; ++m) {
            int j = T16(m);
            a[j] = cmul(a[j], cmul(wb[m >> 2], wa[m & 3]));
        }
    }
    {
        const int wb0 = t << 4;
#pragma unroll
        for (int j = 0; j < 16; ++j) Z[wb0 + (T16(j) ^ tl)] = a[j];
    }
    __syncthreads();

    // ======== stage 1: s=16, n=256 ========
    const int rb = t ^ ((t >> 4) & 15);   // phys base for slots t+256l
#pragma unroll
    for (int l = 0; l < 16; ++l) a[l] = Z[rb + (l << 8)];
    __syncthreads();   // in-place exchange: all reads before any writes
    dft16(a);
    {
        const int p = t >> 4;
        float ang = -0.02454369260617026f * (float)p;  // -2pi/256 * p
        float sn, cs; __sincosf(ang, &sn, &cs);
        cplx w1 = cplx{cs, sn};
        cplx w2 = cmul(w1, w1), w3 = cmul(w2, w1);
        cplx w4 = cmul(w2, w2), w8 = cmul(w4, w4), w12 = cmul(w8, w4);
        cplx wa[4] = {cplx{1.f, 0.f}, w1, w2, w3};
        cplx wb[4] = {cplx{1.f, 0.f}, w4, w8, w12};
#pragma unroll
        for (int m = 1; m < 16; ++m) {
            int j = T16(m);
            a[j] = cmul(a[j], cmul(wb[m >> 2], wa[m & 3]));
        }
    }
    {
        const int base1 = (t >> 4) << 8;   // 256p
#pragma unroll
        for (int m = 0; m < 16; ++m) {
            Z[base1 + (m << 4) + (tl ^ m)] = a[T16(m)];
        }
    }
    __syncthreads();

    // ======== stage 2: s=256, p=0 (no twiddle) ========
#pragma unroll
    for (int l = 0; l < 16; ++l) a[l] = Z[rb + (l << 8)];
    __syncthreads();
    dft16(a);
    // a[T16(m)] = Z4096 bin (t + 256m)

    // ======== export full spectrum: bin b=t+256m -> logical slot 16t+m ========
    {
        const int wb0 = t << 4;
#pragma unroll
        for (int j = 0; j < 16; ++j) Z[wb0 + (T16(j) ^ tl)] = a[j];
    }
    __syncthreads();

    // ======== band sum: bins [273,1706] == {t+256m : m in [1,6]}, each once ========
    // rfft split X[k] = 0.5*((Zk+conj(Zn)) - i*wk*(Zk-conj(Zn))), Zn = Z[(4096-k)&4095].
    // Zk always in regs; Zn one b64 LDS read; wk = wku * e^{-i pi m/16} (const, no chain).
    float band = 0.f;
    {
        float ang = -7.669903939428206e-4f * (float)t;  // -pi/4096 * t
        float sn, cs; __sincosf(ang, &sn, &cs);
        cplx wku = cplx{cs, sn};
        // e^{-i pi m/16}, m=1..6 (compile-time; unrolled loop folds the index)
        const float WCc[7] = {1.f, 0.9807852804032304f, 0.9238795325112867f,
                              0.8314696123025452f, 0.7071067811865476f,
                              0.5555702330196022f, 0.3826834323650898f};
        const float WCs[7] = {0.f, -0.19509032201612825f, -0.3826834323650898f,
                              -0.5555702330196022f, -0.7071067811865476f,
                              -0.8314696123025452f, -0.9238795325112867f};
        // Zn phys addr: t>=1: ((256-t)<<4) | ((15-m) ^ ((16-tl)&15)); t==0: 16-m
        const int pc = ((256 - t) & 255) << 4;
        const int pl = (16 - tl) & 15;
#pragma unroll
        for (int m = 1; m <= 6; ++m) {
            const int k = t + (m << 8);
            const int za = t ? (pc | ((15 - m) ^ pl)) : (16 - m);
            cplx Zk = a[T16(m)];
            cplx Zn = Z[za];
            cplx wk = cmul(wku, cplx{WCc[m], WCs[m]});
            cplx Znc = cplx{Zn.x, -Zn.y};
            cplx s  = Zk + Znc;
            cplx dd = Zk - Znc;
            cplx tt = cmul(wk, dd);
            cplx X  = s + cplx{tt.y, -tt.x};   // 2*X[k]
            float P = (X.x * X.x + X.y * X.y) * (1.0f / 32768.0f);
            if ((unsigned)(k - 273) <= 1433u) band += P;   // k in [273,1706]
        }
    }

    // ======== caps: threads 0..5 recompute bins {r-1,r,r+1,2r-1,2r,2r+1} ========
    // Bins > 2048 come out as the Pn side of k' = 4096-c. Bin 2048 self-pairs.
    float capP = 0.f;
    if (t < 6) {
        const int c = (t < 3) ? (r - 1 + t) : (2 * r - 4 + t);
        const int kk = (c <= 2048) ? c : (4096 - c);
        const int nb = (4096 - kk) & 4095;
        const int zka = ((kk & 255) << 4) | ((kk >> 8) ^ (kk & 15));
        const int zna = ((nb & 255) << 4) | ((nb >> 8) ^ (nb & 15));
        cplx Zk = Z[zka], Zn = Z[zna];
        float ang = -7.669903939428206e-4f * (float)kk;  // -pi/4096 * kk
        float sn, cs; __sincosf(ang, &sn, &cs);
        cplx wk = cplx{cs, sn};
        cplx Znc = cplx{Zn.x, -Zn.y};
        cplx s  = Zk + Znc;
        cplx dd = Zk - Znc;
        cplx tt = cmul(wk, dd);
        cplx X  = (c <= 2048) ? (s + cplx{tt.y, -tt.x})    // 2*X[kk]
                              : (s + cplx{-tt.y, tt.x});   // 2*conj(X[4096-kk])
        capP = (X.x * X.x + X.y * X.y) * (1.0f / 32768.0f);
    }
    __syncthreads();   // ALL Z reads (split + caps) done -> zf overlay safe

    if (t < 6) zf[t] = capP;

    // ---- block reduce band ----
#pragma unroll
    for (int off = 32; off > 0; off >>= 1) band += __shfl_down(band, off);
    if ((t & 63) == 0) zf[8 + (t >> 6)] = band;
    __syncthreads();

    if (t == 0) {
        float bb = zf[8] + zf[9] + zf[10] + zf[11];
        float S = zf[1] + zf[4] + 0.5f * (zf[0] + zf[2]);
        float noise = bb;
        const int r2 = 2 * r;
        if (r <= 1706)      noise -= zf[1];
        if (r - 1 >= 273)   noise -= 0.5f * zf[0];
        if (r + 1 <= 1706)  noise -= 0.5f * zf[2];
        if (r2 - 1 <= 1706) noise -= zf[3];
        if (r2 <= 1706)     noise -= zf[4];
        if (r2 + 1 <= 1706) noise -= zf[5];
        float loss = -10.0f * log10f(S / (noise + 1.0f));
        atomicAdd(out, loss * (1.0f / 4096.0f));
    }
}

extern "C" void kernel_launch(void* const* d_in, const int* in_sizes, int n_in,
                              void* d_out, int out_size, void* d_ws, size_t ws_size,
                              hipStream_t stream) {
    const float* x = (const float*)d_in[0];    // outputs: (4096, 8192) fp32
    const float* tg = (const float*)d_in[1];   // targets: (4096, 1) fp32
    float* out = (float*)d_out;                // scalar fp32
    hipMemsetAsync(out, 0, sizeof(float), stream);
    snr_kernel<<<4096, TPB, 0, stream>>>(x, tg, out);
}